// Round 1
// 661.357 us; speedup vs baseline: 1.0364x; 1.0364x over previous
//
#include <hip/hip_runtime.h>

// Problem constants
#define BB   64
#define NN   4096
#define EE   8192
#define DD   256
#define HH   256
#define MM   64
#define K1   512          // 2*D
#define NC   384          // H + 128 fused GEMM1 cols
#define TE   64           // edges per block
#define BLOCK 512         // 8 waves
#define KC   32
#define NCHUNK 16         // K1/KC
#define ASTR 40           // shorts per A row (32 + 8 pad) -> 80B, 16B-aligned, 2-way banks
#define GSTR 136          // shorts per Gs row (128 + 8 pad)
#define ABUF 2560         // 64*40 shorts per A buffer
#define BE_TOT (BB * EE)  // 524288
#define WCTF_ELEMS (NC * K1)   // 196608
#define A2F_ELEMS  (128 * MM)  // 8192
#define WS_NEEDED ((size_t)(WCTF_ELEMS + A2F_ELEMS) * sizeof(short))  // 409600

typedef float f32x4 __attribute__((ext_vector_type(4)));
typedef short bf16x8 __attribute__((ext_vector_type(8)));

__device__ __forceinline__ short f2bf(float f) {
    unsigned u = __float_as_uint(f);
    unsigned r = (u + 0x7fffu + ((u >> 16) & 1u)) >> 16;
    return (short)r;
}

// Barrier that only drains LDS ops (ds_write visibility) — leaves global
// loads (gather prefetch, B-frag prefetch: both land in VGPRs) in flight.
// __syncthreads() would emit s_waitcnt vmcnt(0) and kill the prefetch.
__device__ __forceinline__ void barrier_lgkm() {
    asm volatile("s_waitcnt lgkmcnt(0)\n\ts_barrier" ::: "memory");
}

// Prep: write weights in MFMA B-fragment order (bf16).
__global__ void AttackHead_prep(const float* __restrict__ W1,
                                const float* __restrict__ A1,
                                const float* __restrict__ A2,
                                short* __restrict__ wctf,
                                short* __restrict__ a2f) {
    int t = blockIdx.x * 256 + threadIdx.x;
    if (t < 131072) {                       // W1 [512][256], coalesced read
        int k = t >> 8, n = t & 255;
        int c = k >> 5, kr = k & 31, quad = kr >> 3, j = kr & 7;
        int nt = n >> 4, l15 = n & 15;
        wctf[((c * 24 + nt) * 64 + quad * 16 + l15) * 8 + j] = f2bf(W1[t]);
    } else if (t < 131072 + 65536) {        // A1 [512][128]
        int t2 = t - 131072;
        int k = t2 >> 7, n = 256 + (t2 & 127);
        int c = k >> 5, kr = k & 31, quad = kr >> 3, j = kr & 7;
        int nt = n >> 4, l15 = n & 15;
        wctf[((c * 24 + nt) * 64 + quad * 16 + l15) * 8 + j] = f2bf(A1[t2]);
    } else if (t < 131072 + 65536 + 8192) { // A2 [128][64]
        int t3 = t - 131072 - 65536;
        int k = t3 >> 6, n = t3 & 63;
        int ks = k >> 5, kr = k & 31, quad = kr >> 3, j = kr & 7;
        int nt2 = n >> 4, l15 = n & 15;
        a2f[((ks * 4 + nt2) * 64 + quad * 16 + l15) * 8 + j] = f2bf(A2[t3]);
    }
}

template <bool USE_WS>
__device__ __forceinline__ bf16x8 load_bfrag(const short* __restrict__ wf,
                                             const float* __restrict__ W1,
                                             const float* __restrict__ A1,
                                             int c, int nt, int lane) {
    if (USE_WS) {
        return *(const bf16x8*)(wf + ((c * 24 + nt) * 64 + lane) * 8);
    } else {
        int l15 = lane & 15, quad = lane >> 4;
        int n = nt * 16 + l15;
        bf16x8 r;
        #pragma unroll
        for (int j = 0; j < 8; ++j) {
            int k = c * KC + quad * 8 + j;
            float v = (n < HH) ? W1[k * HH + n] : A1[k * 128 + (n - HH)];
            r[j] = f2bf(v);
        }
        return r;
    }
}

template <bool USE_WS>
__device__ __forceinline__ bf16x8 load_a2frag(const short* __restrict__ a2f,
                                              const float* __restrict__ A2,
                                              int ks, int nt2, int lane) {
    if (USE_WS) {
        return *(const bf16x8*)(a2f + ((ks * 4 + nt2) * 64 + lane) * 8);
    } else {
        int l15 = lane & 15, quad = lane >> 4;
        int n = nt2 * 16 + l15;
        bf16x8 r;
        #pragma unroll
        for (int j = 0; j < 8; ++j) {
            int k = ks * 32 + quad * 8 + j;
            r[j] = f2bf(A2[k * MM + n]);
        }
        return r;
    }
}

template <bool USE_WS>
__global__ __launch_bounds__(BLOCK, 4)
void AttackHead_main(const float* __restrict__ nodes,
                     const float* __restrict__ army,
                     const int* __restrict__ edges,
                     const float* __restrict__ W1,
                     const float* __restrict__ b1,
                     const float* __restrict__ W2,
                     const float* __restrict__ b2,
                     const float* __restrict__ A1,
                     const float* __restrict__ a1,
                     const float* __restrict__ A2,
                     const float* __restrict__ a2,
                     const short* __restrict__ wctf,
                     const short* __restrict__ a2f,
                     float* __restrict__ out) {
    // LDS: union of {3 A-buffers (3*2560=7680 shorts)} and {Gs 64x136=8704 shorts}
    __shared__ __align__(16) short smem[8704];   // 17408 B
    __shared__ int   srcn[TE], tgtn[TE];
    __shared__ float elog[TE], maxs[TE];

    const int tid = threadIdx.x;
    // XCD-contiguous swizzle: XCD k (= blockIdx.x % 8 under round-robin
    // dispatch) processes logical blocks [k*1024, (k+1)*1024) = batches
    // [k*8, k*8+8) sequentially -> one batch's 4MB node set stays L2-resident.
    const int bb  = ((blockIdx.x & 7) << 10) | (blockIdx.x >> 3);
    const int bglob = bb >> 7;              // bb / (EE/TE) = bb/128
    const long be0 = (long)bb * TE;

    // ---- Phase 0: edge scalars ----
    if (tid < TE) {
        long be = be0 + tid;
        int src = edges[2 * be], tgt = edges[2 * be + 1];
        int sc = min(max(src, 0), NN - 1);
        int tc = min(max(tgt, 0), NN - 1);
        srcn[tid] = sc; tgtn[tid] = tc;
        float sa = army[(size_t)bglob * NN + sc];
        float ta = army[(size_t)bglob * NN + tc];
        bool valid = (src >= 0) && (tgt >= 0);
        bool bad   = valid && (sa <= 2.0f || ta >= 3.0f * sa);
        bool selfe = valid && (src == tgt);
        elog[tid] = b2[0] - (bad ? 1.0f : 0.0f) - (selfe ? 100.0f : 0.0f);
        maxs[tid] = sa - 1.0f;
    }

    const int w    = tid >> 6;     // wave 0..7
    const int lane = tid & 63;
    const int quad = lane >> 4;
    const int l15  = lane & 15;

    // B-fragment prefetch for chunk 0 (independent of phase 0 / LDS)
    bf16x8 bfn0 = load_bfrag<USE_WS>(wctf, W1, A1, 0, w * 3 + 0, lane);
    bf16x8 bfn1 = load_bfrag<USE_WS>(wctf, W1, A1, 0, w * 3 + 1, lane);
    bf16x8 bfn2 = load_bfrag<USE_WS>(wctf, W1, A1, 0, w * 3 + 2, lane);

    __syncthreads();

    // staging role: 8 threads per row, 4 floats each
    const int srow = tid >> 3;     // 0..63
    const int sj   = tid & 7;      // float4 index within 32-float chunk
    const size_t nbase_g = (size_t)bglob * NN;

    f32x4 acc[4][3] = {};          // [m-tile][n-tile] ; wave's n-tiles = w*3 + jn

    // ---- Prologue: stage chunk 0, issue chunk 1 ----
    {
        int node = srcn[srow];
        float4 v = *(const float4*)(nodes + (nbase_g + node) * DD + sj * 4);
        short4 s;
        s.x = f2bf(v.x); s.y = f2bf(v.y); s.z = f2bf(v.z); s.w = f2bf(v.w);
        *(short4*)(&smem[0 * ABUF + srow * ASTR + sj * 4]) = s;
    }
    float4 lda = *(const float4*)(nodes + (nbase_g + srcn[srow]) * DD + KC + sj * 4);

    int bufc = 0;
    for (int c = 0; c < NCHUNK; ++c) {
        barrier_lgkm();            // buf[bufc] ready; global prefetches stay in flight

        // distance-2 gather prefetch: issue chunk c+2
        float4 ldn;
        if (c + 2 < NCHUNK) {
            int cc = c + 2;
            int node = (cc < 8) ? srcn[srow] : tgtn[srow];
            ldn = *(const float4*)(nodes + (nbase_g + node) * DD + (cc & 7) * KC + sj * 4);
        }

        // consume prefetched B fragments; issue next chunk's B loads
        bf16x8 bf0 = bfn0, bf1 = bfn1, bf2 = bfn2;
        if (c + 1 < NCHUNK) {
            bfn0 = load_bfrag<USE_WS>(wctf, W1, A1, c + 1, w * 3 + 0, lane);
            bfn1 = load_bfrag<USE_WS>(wctf, W1, A1, c + 1, w * 3 + 1, lane);
            bfn2 = load_bfrag<USE_WS>(wctf, W1, A1, c + 1, w * 3 + 2, lane);
        }

        // A fragments from LDS
        const short* Ab = &smem[bufc * ABUF];
        bf16x8 af[4];
        #pragma unroll
        for (int mt = 0; mt < 4; ++mt)
            af[mt] = *(const bf16x8*)(&Ab[(mt * 16 + l15) * ASTR + quad * 8]);

        #pragma unroll
        for (int mt = 0; mt < 4; ++mt) {
            acc[mt][0] = __builtin_amdgcn_mfma_f32_16x16x32_bf16(af[mt], bf0, acc[mt][0], 0, 0, 0);
            acc[mt][1] = __builtin_amdgcn_mfma_f32_16x16x32_bf16(af[mt], bf1, acc[mt][1], 0, 0, 0);
            acc[mt][2] = __builtin_amdgcn_mfma_f32_16x16x32_bf16(af[mt], bf2, acc[mt][2], 0, 0, 0);
        }

        // stage chunk c+1 into next buffer
        int bufw = (bufc + 1 == 3) ? 0 : bufc + 1;
        if (c + 1 < NCHUNK) {
            short4 s;
            s.x = f2bf(lda.x); s.y = f2bf(lda.y); s.z = f2bf(lda.z); s.w = f2bf(lda.w);
            *(short4*)(&smem[bufw * ABUF + srow * ASTR + sj * 4]) = s;
            lda = ldn;
        }
        bufc = bufw;
    }

    __syncthreads();   // full drain: all reads of A buffers done; Gs reuse safe

    // ---- Epilogue 1: bias+relu; edge-logit partials; relu(g) -> Gs ----
    short* Gs = smem;
    float ep[4][4] = {};
    #pragma unroll
    for (int jn = 0; jn < 3; ++jn) {
        int ct = (w * 3 + jn) * 16 + l15;
        float bias = (ct < HH) ? b1[ct] : a1[ct - HH];
        if (ct < HH) {
            float w2v = W2[ct];
            #pragma unroll
            for (int mt = 0; mt < 4; ++mt)
                #pragma unroll
                for (int r = 0; r < 4; ++r) {
                    float h = fmaxf(acc[mt][jn][r] + bias, 0.0f);
                    ep[mt][r] += h * w2v;
                }
        } else {
            int gc = ct - HH;
            #pragma unroll
            for (int mt = 0; mt < 4; ++mt)
                #pragma unroll
                for (int r = 0; r < 4; ++r) {
                    float g = fmaxf(acc[mt][jn][r] + bias, 0.0f);
                    Gs[(mt * 16 + quad * 4 + r) * GSTR + gc] = f2bf(g);
                }
        }
    }
    if (w < 6) {   // waves 6,7 have no h-columns
        #pragma unroll
        for (int msk = 1; msk <= 8; msk <<= 1)
            #pragma unroll
            for (int mt = 0; mt < 4; ++mt)
                #pragma unroll
                for (int r = 0; r < 4; ++r)
                    ep[mt][r] += __shfl_xor(ep[mt][r], msk, 64);
        if (l15 == 0) {
            #pragma unroll
            for (int mt = 0; mt < 4; ++mt)
                #pragma unroll
                for (int r = 0; r < 4; ++r)
                    atomicAdd(&elog[mt * 16 + quad * 4 + r], ep[mt][r]);
        }
    }
    __syncthreads();

    // ---- GEMM2: relu(g)[64,128] @ A2[128,64] ----
    const int mt2 = w >> 1;      // m-tile 0..3
    const int nh  = w & 1;       // n-half
    f32x4 acc2[2] = {};
    #pragma unroll
    for (int ks = 0; ks < 4; ++ks) {
        bf16x8 ga = *(const bf16x8*)(&Gs[(mt2 * 16 + l15) * GSTR + ks * 32 + quad * 8]);
        #pragma unroll
        for (int nb = 0; nb < 2; ++nb) {
            bf16x8 bv = load_a2frag<USE_WS>(a2f, A2, ks, nh * 2 + nb, lane);
            acc2[nb] = __builtin_amdgcn_mfma_f32_16x16x32_bf16(ga, bv, acc2[nb], 0, 0, 0);
        }
    }

    // ---- Outputs ----
    if (tid < TE) out[be0 + tid] = elog[tid];

    #pragma unroll
    for (int nb = 0; nb < 2; ++nb) {
        int col = (nh * 2 + nb) * 16 + l15;
        float a2v = a2[col];
        #pragma unroll
        for (int r = 0; r < 4; ++r) {
            int grow = mt2 * 16 + quad * 4 + r;
            float val = acc2[nb][r] + a2v;
            if ((float)col > maxs[grow]) val = -1e9f;
            out[(size_t)BE_TOT + (size_t)(be0 + grow) * MM + col] = val;
        }
    }
}

extern "C" void kernel_launch(void* const* d_in, const int* in_sizes, int n_in,
                              void* d_out, int out_size, void* d_ws, size_t ws_size,
                              hipStream_t stream) {
    const float* nodes = (const float*)d_in[0];
    const float* army  = (const float*)d_in[1];
    const int*   edges = (const int*)d_in[2];
    const float* W1    = (const float*)d_in[3];
    const float* b1    = (const float*)d_in[4];
    const float* W2    = (const float*)d_in[5];
    const float* b2    = (const float*)d_in[6];
    const float* A1    = (const float*)d_in[7];
    const float* a1    = (const float*)d_in[8];
    const float* A2    = (const float*)d_in[9];
    const float* a2    = (const float*)d_in[10];
    float* out = (float*)d_out;

    int nblocks = BE_TOT / TE;   // 8192

    if (ws_size >= WS_NEEDED) {
        short* wctf = (short*)d_ws;
        short* a2f  = wctf + WCTF_ELEMS;
        AttackHead_prep<<<800, 256, 0, stream>>>(W1, A1, A2, wctf, a2f);
        AttackHead_main<true><<<nblocks, BLOCK, 0, stream>>>(
            nodes, army, edges, W1, b1, W2, b2, A1, a1, A2, a2, wctf, a2f, out);
    } else {
        AttackHead_main<false><<<nblocks, BLOCK, 0, stream>>>(
            nodes, army, edges, W1, b1, W2, b2, A1, a1, A2, a2,
            (const short*)nullptr, (const short*)nullptr, out);
    }
}

// Round 3
// 642.380 us; speedup vs baseline: 1.0671x; 1.0295x over previous
//
#include <hip/hip_runtime.h>

// Problem constants
#define BB   64
#define NN   4096
#define EE   8192
#define DD   256
#define HH   256
#define MM   64
#define K1   512          // 2*D
#define NC   384          // H + 128 fused GEMM1 cols
#define TE   64           // edges per block
#define BLOCK 512         // 8 waves
#define KC   64           // k-elems per chunk (2 MFMA k-steps) -> 8 barriers, not 16
#define NCHUNK 8          // K1/KC
#define ASTR 88           // shorts per A row (64 + 24 pad): 176B stride, balanced banks
#define GSTR 136          // shorts per Gs row (128 + 8 pad)
#define ABUF (64 * ASTR)  // 5632 shorts per A buffer
#define SMEM_SHORTS (2 * ABUF)  // 11264 shorts >= Gs 64*136=8704
#define BE_TOT (BB * EE)  // 524288
#define WCTF_ELEMS (NC * K1)   // 196608
#define A2F_ELEMS  (128 * MM)  // 8192
#define WS_NEEDED ((size_t)(WCTF_ELEMS + A2F_ELEMS) * sizeof(short))  // 409600

typedef float f32x4 __attribute__((ext_vector_type(4)));
typedef short bf16x8 __attribute__((ext_vector_type(8)));

__device__ __forceinline__ short f2bf(float f) {
    unsigned u = __float_as_uint(f);
    unsigned r = (u + 0x7fffu + ((u >> 16) & 1u)) >> 16;
    return (short)r;
}

// Packed f32->bf16 RNE conversion: 2 floats -> 1 dword in ONE VALU op
// (identical rounding to f2bf's manual round-to-nearest-even).
__device__ __forceinline__ int cvt_pk_bf16(float lo, float hi) {
    int r;
    asm("v_cvt_pk_bf16_f32 %0, %1, %2" : "=v"(r) : "v"(lo), "v"(hi));
    return r;
}

// Barrier that only drains LDS ops — leaves global loads (gather prefetch,
// B-frag prefetch: both land in VGPRs) in flight across the barrier.
__device__ __forceinline__ void barrier_lgkm() {
    asm volatile("s_waitcnt lgkmcnt(0)\n\ts_barrier" ::: "memory");
}

// Prep: write weights in MFMA B-fragment order (bf16).
__global__ void AttackHead_prep(const float* __restrict__ W1,
                                const float* __restrict__ A1,
                                const float* __restrict__ A2,
                                short* __restrict__ wctf,
                                short* __restrict__ a2f) {
    int t = blockIdx.x * 256 + threadIdx.x;
    if (t < 131072) {                       // W1 [512][256], coalesced read
        int k = t >> 8, n = t & 255;
        int c = k >> 5, kr = k & 31, quad = kr >> 3, j = kr & 7;
        int nt = n >> 4, l15 = n & 15;
        wctf[((c * 24 + nt) * 64 + quad * 16 + l15) * 8 + j] = f2bf(W1[t]);
    } else if (t < 131072 + 65536) {        // A1 [512][128]
        int t2 = t - 131072;
        int k = t2 >> 7, n = 256 + (t2 & 127);
        int c = k >> 5, kr = k & 31, quad = kr >> 3, j = kr & 7;
        int nt = n >> 4, l15 = n & 15;
        wctf[((c * 24 + nt) * 64 + quad * 16 + l15) * 8 + j] = f2bf(A1[t2]);
    } else if (t < 131072 + 65536 + 8192) { // A2 [128][64]
        int t3 = t - 131072 - 65536;
        int k = t3 >> 6, n = t3 & 63;
        int ks = k >> 5, kr = k & 31, quad = kr >> 3, j = kr & 7;
        int nt2 = n >> 4, l15 = n & 15;
        a2f[((ks * 4 + nt2) * 64 + quad * 16 + l15) * 8 + j] = f2bf(A2[t3]);
    }
}

template <bool USE_WS>
__device__ __forceinline__ bf16x8 load_bfrag(const short* __restrict__ wf,
                                             const float* __restrict__ W1,
                                             const float* __restrict__ A1,
                                             int c, int nt, int lane) {
    if (USE_WS) {
        return *(const bf16x8*)(wf + ((c * 24 + nt) * 64 + lane) * 8);
    } else {
        int l15 = lane & 15, quad = lane >> 4;
        int n = nt * 16 + l15;
        bf16x8 r;
        #pragma unroll
        for (int j = 0; j < 8; ++j) {
            int k = c * 32 + quad * 8 + j;
            float v = (n < HH) ? W1[k * HH + n] : A1[k * 128 + (n - HH)];
            r[j] = f2bf(v);
        }
        return r;
    }
}

template <bool USE_WS>
__device__ __forceinline__ bf16x8 load_a2frag(const short* __restrict__ a2f,
                                              const float* __restrict__ A2,
                                              int ks, int nt2, int lane) {
    if (USE_WS) {
        return *(const bf16x8*)(a2f + ((ks * 4 + nt2) * 64 + lane) * 8);
    } else {
        int l15 = lane & 15, quad = lane >> 4;
        int n = nt2 * 16 + l15;
        bf16x8 r;
        #pragma unroll
        for (int j = 0; j < 8; ++j) {
            int k = ks * 32 + quad * 8 + j;
            r[j] = f2bf(A2[k * MM + n]);
        }
        return r;
    }
}

template <bool USE_WS>
__global__ __launch_bounds__(BLOCK, 4)
void AttackHead_main(const float* __restrict__ nodes,
                     const float* __restrict__ army,
                     const int* __restrict__ edges,
                     const float* __restrict__ W1,
                     const float* __restrict__ b1,
                     const float* __restrict__ W2,
                     const float* __restrict__ b2,
                     const float* __restrict__ A1,
                     const float* __restrict__ a1,
                     const float* __restrict__ A2,
                     const float* __restrict__ a2,
                     const short* __restrict__ wctf,
                     const short* __restrict__ a2f,
                     float* __restrict__ out) {
    // LDS: union of {2 A-buffers (2*5632 shorts)} and {Gs 64x136=8704 shorts}
    __shared__ __align__(16) short smem[SMEM_SHORTS];   // 22528 B
    __shared__ int   srcn[TE], tgtn[TE];
    __shared__ float elog[TE], maxs[TE];

    const int tid = threadIdx.x;
    // XCD-contiguous swizzle: each XCD walks 8 consecutive batches -> the
    // batch's 4MB node set stays L2-resident (R1: FETCH 465->205 MB).
    const int bb  = ((blockIdx.x & 7) << 10) | (blockIdx.x >> 3);
    const int bglob = bb >> 7;              // bb / (EE/TE) = bb/128
    const long be0 = (long)bb * TE;

    // ---- Phase 0: edge scalars ----
    if (tid < TE) {
        long be = be0 + tid;
        int src = edges[2 * be], tgt = edges[2 * be + 1];
        int sc = min(max(src, 0), NN - 1);
        int tc = min(max(tgt, 0), NN - 1);
        srcn[tid] = sc; tgtn[tid] = tc;
        float sa = army[(size_t)bglob * NN + sc];
        float ta = army[(size_t)bglob * NN + tc];
        bool valid = (src >= 0) && (tgt >= 0);
        bool bad   = valid && (sa <= 2.0f || ta >= 3.0f * sa);
        bool selfe = valid && (src == tgt);
        elog[tid] = b2[0] - (bad ? 1.0f : 0.0f) - (selfe ? 100.0f : 0.0f);
        maxs[tid] = sa - 1.0f;
    }

    const int w    = tid >> 6;     // wave 0..7
    const int lane = tid & 63;
    const int quad = lane >> 4;
    const int l15  = lane & 15;

    // B-fragment prefetch for iter 0 / kk=0 (independent of phase 0 / LDS)
    bf16x8 bfc0 = load_bfrag<USE_WS>(wctf, W1, A1, 0, w * 3 + 0, lane);
    bf16x8 bfc1 = load_bfrag<USE_WS>(wctf, W1, A1, 0, w * 3 + 1, lane);
    bf16x8 bfc2 = load_bfrag<USE_WS>(wctf, W1, A1, 0, w * 3 + 2, lane);

    __syncthreads();

    // staging role: 8 threads per row, 8 floats each (KC=64 per chunk)
    const int srow = tid >> 3;     // 0..63
    const int sj   = tid & 7;      // 8-float slice index within 64-float chunk
    const size_t nbase_g = (size_t)bglob * NN;
    // hoisted gather bases: per-iter addresses become compile-time offsets
    const float* srcp = nodes + (nbase_g + (size_t)srcn[srow]) * DD + sj * 8;
    const float* tgtp = nodes + (nbase_g + (size_t)tgtn[srow]) * DD + sj * 8;

    f32x4 acc[4][3] = {};          // [m-tile][n-tile] ; wave's n-tiles = w*3 + jn

    // ---- Prologue: stage chunk 0, issue chunk 1 ----
    {
        float4 v0 = *(const float4*)(srcp);
        float4 v1 = *(const float4*)(srcp + 4);
        int4 s;
        s.x = cvt_pk_bf16(v0.x, v0.y); s.y = cvt_pk_bf16(v0.z, v0.w);
        s.z = cvt_pk_bf16(v1.x, v1.y); s.w = cvt_pk_bf16(v1.z, v1.w);
        *(int4*)(&smem[srow * ASTR + sj * 8]) = s;
    }
    float4 lda0 = *(const float4*)(srcp + 64);
    float4 lda1 = *(const float4*)(srcp + 68);

    #pragma unroll
    for (int c = 0; c < NCHUNK; ++c) {
        barrier_lgkm();            // buf[c&1] ready; global prefetches stay in flight

        // distance-2 gather prefetch: issue chunk c+2 (chunks 0-3 src, 4-7 tgt)
        float4 ldn0, ldn1;
        if (c + 2 < NCHUNK) {
            const float* p = ((c + 2) < 4 ? srcp : tgtp) + ((c + 2) & 3) * 64;
            ldn0 = *(const float4*)(p);
            ldn1 = *(const float4*)(p + 4);
        }

        // kk=1 B-frags for THIS iter (cover = kk=0 MFMA block)
        bf16x8 bg0 = load_bfrag<USE_WS>(wctf, W1, A1, 2 * c + 1, w * 3 + 0, lane);
        bf16x8 bg1 = load_bfrag<USE_WS>(wctf, W1, A1, 2 * c + 1, w * 3 + 1, lane);
        bf16x8 bg2 = load_bfrag<USE_WS>(wctf, W1, A1, 2 * c + 1, w * 3 + 2, lane);

        const short* Ab = &smem[(c & 1) * ABUF];

        // kk=0: A frags + MFMA (B frags prefetched last iter, already in VGPRs)
        bf16x8 af[4];
        #pragma unroll
        for (int mt = 0; mt < 4; ++mt)
            af[mt] = *(const bf16x8*)(&Ab[(mt * 16 + l15) * ASTR + quad * 8]);
        #pragma unroll
        for (int mt = 0; mt < 4; ++mt) {
            acc[mt][0] = __builtin_amdgcn_mfma_f32_16x16x32_bf16(af[mt], bfc0, acc[mt][0], 0, 0, 0);
            acc[mt][1] = __builtin_amdgcn_mfma_f32_16x16x32_bf16(af[mt], bfc1, acc[mt][1], 0, 0, 0);
            acc[mt][2] = __builtin_amdgcn_mfma_f32_16x16x32_bf16(af[mt], bfc2, acc[mt][2], 0, 0, 0);
        }

        // next-iter kk=0 B-frag prefetch (consumed after next barrier)
        if (c + 1 < NCHUNK) {
            bfc0 = load_bfrag<USE_WS>(wctf, W1, A1, 2 * c + 2, w * 3 + 0, lane);
            bfc1 = load_bfrag<USE_WS>(wctf, W1, A1, 2 * c + 2, w * 3 + 1, lane);
            bfc2 = load_bfrag<USE_WS>(wctf, W1, A1, 2 * c + 2, w * 3 + 2, lane);
        }

        // kk=1: A frags + MFMA
        bf16x8 ag[4];
        #pragma unroll
        for (int mt = 0; mt < 4; ++mt)
            ag[mt] = *(const bf16x8*)(&Ab[(mt * 16 + l15) * ASTR + 32 + quad * 8]);
        #pragma unroll
        for (int mt = 0; mt < 4; ++mt) {
            acc[mt][0] = __builtin_amdgcn_mfma_f32_16x16x32_bf16(ag[mt], bg0, acc[mt][0], 0, 0, 0);
            acc[mt][1] = __builtin_amdgcn_mfma_f32_16x16x32_bf16(ag[mt], bg1, acc[mt][1], 0, 0, 0);
            acc[mt][2] = __builtin_amdgcn_mfma_f32_16x16x32_bf16(ag[mt], bg2, acc[mt][2], 0, 0, 0);
        }

        // stage chunk c+1 into the other buffer (2 buffers suffice: the
        // lgkm barrier at iter start drained last iter's reads of it)
        if (c + 1 < NCHUNK) {
            int4 s;
            s.x = cvt_pk_bf16(lda0.x, lda0.y); s.y = cvt_pk_bf16(lda0.z, lda0.w);
            s.z = cvt_pk_bf16(lda1.x, lda1.y); s.w = cvt_pk_bf16(lda1.z, lda1.w);
            *(int4*)(&smem[((c + 1) & 1) * ABUF + srow * ASTR + sj * 8]) = s;
        }
        if (c + 2 < NCHUNK) { lda0 = ldn0; lda1 = ldn1; }
    }

    __syncthreads();   // full drain: all reads of A buffers done; Gs reuse safe

    // ---- Epilogue 1: bias+relu; edge-logit partials; relu(g) -> Gs ----
    short* Gs = smem;
    float ep[4][4] = {};
    #pragma unroll
    for (int jn = 0; jn < 3; ++jn) {
        int ct = (w * 3 + jn) * 16 + l15;
        float bias = (ct < HH) ? b1[ct] : a1[ct - HH];
        if (ct < HH) {
            float w2v = W2[ct];
            #pragma unroll
            for (int mt = 0; mt < 4; ++mt)
                #pragma unroll
                for (int r = 0; r < 4; ++r) {
                    float h = fmaxf(acc[mt][jn][r] + bias, 0.0f);
                    ep[mt][r] += h * w2v;
                }
        } else {
            int gc = ct - HH;
            #pragma unroll
            for (int mt = 0; mt < 4; ++mt)
                #pragma unroll
                for (int r = 0; r < 4; ++r) {
                    float g = fmaxf(acc[mt][jn][r] + bias, 0.0f);
                    Gs[(mt * 16 + quad * 4 + r) * GSTR + gc] = f2bf(g);
                }
        }
    }
    if (w < 6) {   // waves 6,7 have no h-columns
        #pragma unroll
        for (int msk = 1; msk <= 8; msk <<= 1)
            #pragma unroll
            for (int mt = 0; mt < 4; ++mt)
                #pragma unroll
                for (int r = 0; r < 4; ++r)
                    ep[mt][r] += __shfl_xor(ep[mt][r], msk, 64);
        if (l15 == 0) {
            #pragma unroll
            for (int mt = 0; mt < 4; ++mt)
                #pragma unroll
                for (int r = 0; r < 4; ++r)
                    atomicAdd(&elog[mt * 16 + quad * 4 + r], ep[mt][r]);
        }
    }
    __syncthreads();

    // ---- GEMM2: relu(g)[64,128] @ A2[128,64] ----
    const int mt2 = w >> 1;      // m-tile 0..3
    const int nh  = w & 1;       // n-half
    f32x4 acc2[2] = {};
    #pragma unroll
    for (int ks = 0; ks < 4; ++ks) {
        bf16x8 ga = *(const bf16x8*)(&Gs[(mt2 * 16 + l15) * GSTR + ks * 32 + quad * 8]);
        #pragma unroll
        for (int nb = 0; nb < 2; ++nb) {
            bf16x8 bv = load_a2frag<USE_WS>(a2f, A2, ks, nh * 2 + nb, lane);
            acc2[nb] = __builtin_amdgcn_mfma_f32_16x16x32_bf16(ga, bv, acc2[nb], 0, 0, 0);
        }
    }

    // ---- Outputs ----
    if (tid < TE) out[be0 + tid] = elog[tid];

    #pragma unroll
    for (int nb = 0; nb < 2; ++nb) {
        int col = (nh * 2 + nb) * 16 + l15;
        float a2v = a2[col];
        #pragma unroll
        for (int r = 0; r < 4; ++r) {
            int grow = mt2 * 16 + quad * 4 + r;
            float val = acc2[nb][r] + a2v;
            if ((float)col > maxs[grow]) val = -1e9f;
            out[(size_t)BE_TOT + (size_t)(be0 + grow) * MM + col] = val;
        }
    }
}

extern "C" void kernel_launch(void* const* d_in, const int* in_sizes, int n_in,
                              void* d_out, int out_size, void* d_ws, size_t ws_size,
                              hipStream_t stream) {
    const float* nodes = (const float*)d_in[0];
    const float* army  = (const float*)d_in[1];
    const int*   edges = (const int*)d_in[2];
    const float* W1    = (const float*)d_in[3];
    const float* b1    = (const float*)d_in[4];
    const float* W2    = (const float*)d_in[5];
    const float* b2    = (const float*)d_in[6];
    const float* A1    = (const float*)d_in[7];
    const float* a1    = (const float*)d_in[8];
    const float* A2    = (const float*)d_in[9];
    const float* a2    = (const float*)d_in[10];
    float* out = (float*)d_out;

    int nblocks = BE_TOT / TE;   // 8192

    if (ws_size >= WS_NEEDED) {
        short* wctf = (short*)d_ws;
        short* a2f  = wctf + WCTF_ELEMS;
        AttackHead_prep<<<800, 256, 0, stream>>>(W1, A1, A2, wctf, a2f);
        AttackHead_main<true><<<nblocks, BLOCK, 0, stream>>>(
            nodes, army, edges, W1, b1, W2, b2, A1, a1, A2, a2, wctf, a2f, out);
    } else {
        AttackHead_main<false><<<nblocks, BLOCK, 0, stream>>>(
            nodes, army, edges, W1, b1, W2, b2, A1, a1, A2, a2,
            (const short*)nullptr, (const short*)nullptr, out);
    }
}